// Round 1
// baseline (962.932 us; speedup 1.0000x reference)
//
#include <hip/hip_runtime.h>
#include <hip/hip_bf16.h>

// Problem: B=32, R=5, N=1024, D=256, H=256
// out[b,n,h] = sum_d nodes[b,n,d]*w0[h,d]
//            + sum_r (1/c[b,r,n]) * sum_d nodes[b,n,d]*wr[r,h,d]
// c[b,r,n] = sum_j adj[b,r,n,j]  (1 if 0)

#define BB 32
#define RR 5
#define NN 1024
#define DD 256
#define HH 256
#define MM (BB * NN)   // 32768 global rows

typedef __attribute__((ext_vector_type(8))) short short8;
typedef __attribute__((ext_vector_type(4))) float f32x4;

__device__ __forceinline__ unsigned short f2bf(float f) {
    unsigned int u = __float_as_uint(f);
    unsigned int r = (u + 0x7FFFu + ((u >> 16) & 1u)) >> 16;
    return (unsigned short)r;
}

// fp32 -> bf16 raw bits, 4 elems/thread. n must be multiple of 4.
__global__ void cvt_kernel(const float* __restrict__ in,
                           unsigned short* __restrict__ out, int n) {
    int i = (blockIdx.x * blockDim.x + threadIdx.x) * 4;
    if (i >= n) return;
    float4 v = *reinterpret_cast<const float4*>(in + i);
    ushort4 o;
    o.x = f2bf(v.x); o.y = f2bf(v.y); o.z = f2bf(v.z); o.w = f2bf(v.w);
    *reinterpret_cast<ushort4*>(out + i) = o;
}

// One wave per adjacency row (1024 floats). inv_c[b,r,n] = 1/max(rowsum, treat 0 as 1).
__global__ __launch_bounds__(256) void rowsum_kernel(const float* __restrict__ adj,
                                                     float* __restrict__ inv_c) {
    const int wave = blockIdx.x * 4 + (threadIdx.x >> 6);
    const int lane = threadIdx.x & 63;
    const float4* row4 = reinterpret_cast<const float4*>(adj + (size_t)wave * NN);
    float s = 0.f;
#pragma unroll
    for (int i = 0; i < 4; ++i) {
        float4 v = row4[lane + 64 * i];
        s += (v.x + v.y) + (v.z + v.w);
    }
#pragma unroll
    for (int off = 32; off > 0; off >>= 1) s += __shfl_down(s, off, 64);
    if (lane == 0) {
        float c = (s == 0.f) ? 1.f : s;
        inv_c[wave] = 1.f / c;
    }
}

// Fused 6-set GEMM + per-row combine.
// Block = 256 thr (4 waves). Block tile: 64 rows x 64 cols; wave w: 64 rows x 16 cols.
// nodesb: (M, D) bf16; wb: (6, H, D) bf16 (set 0 = w0, sets 1..5 = wr); out: (M, H) f32.
__global__ __launch_bounds__(256) void gemm_kernel(
    const unsigned short* __restrict__ nodesb,
    const unsigned short* __restrict__ wb,
    const float* __restrict__ inv_c,
    float* __restrict__ out) {
    const int lane = threadIdx.x & 63;
    const int wv   = threadIdx.x >> 6;
    const int row_base = blockIdx.x * 64;
    const int col_base = blockIdx.y * 64 + wv * 16;
    const int m    = lane & 15;
    const int quad = lane >> 4;
    const int kofs = quad * 8;

    f32x4 acc[6][4];
#pragma unroll
    for (int s = 0; s < 6; ++s)
#pragma unroll
        for (int t = 0; t < 4; ++t) acc[s][t] = (f32x4){0.f, 0.f, 0.f, 0.f};

    const unsigned short* aptr = nodesb + (size_t)(row_base + m) * DD + kofs;
    const unsigned short* bptr = wb + (size_t)(col_base + m) * DD + kofs;

#pragma unroll
    for (int k = 0; k < DD; k += 32) {
        short8 afr[4];
#pragma unroll
        for (int t = 0; t < 4; ++t)
            afr[t] = *reinterpret_cast<const short8*>(aptr + (size_t)t * 16 * DD + k);
#pragma unroll
        for (int s = 0; s < 6; ++s) {
            short8 bfr = *reinterpret_cast<const short8*>(bptr + (size_t)s * HH * DD + k);
#pragma unroll
            for (int t = 0; t < 4; ++t)
                acc[s][t] = __builtin_amdgcn_mfma_f32_16x16x32_bf16(afr[t], bfr, acc[s][t], 0, 0, 0);
        }
    }

    // Epilogue: out[row, col] = acc0 + sum_r inv_c[b,r,n] * acc_{r+1}
    const int b  = row_base >> 10;   // row_base / NN (block never spans batches)
    const int n0 = row_base & (NN - 1);
#pragma unroll
    for (int t = 0; t < 4; ++t) {
#pragma unroll
        for (int i = 0; i < 4; ++i) {
            const int rloc = t * 16 + quad * 4 + i;
            const int n = n0 + rloc;
            float v = acc[0][t][i];
#pragma unroll
            for (int r = 0; r < RR; ++r)
                v += inv_c[((size_t)b * RR + r) * NN + n] * acc[r + 1][t][i];
            out[((size_t)(row_base + rloc)) * HH + col_base + m] = v;
        }
    }
}

extern "C" void kernel_launch(void* const* d_in, const int* in_sizes, int n_in,
                              void* d_out, int out_size, void* d_ws, size_t ws_size,
                              hipStream_t stream) {
    const float* nodes = (const float*)d_in[0];  // (B,N,D)
    const float* adj   = (const float*)d_in[1];  // (B,R,N,N)
    const float* w0    = (const float*)d_in[2];  // (H,D)
    const float* wr    = (const float*)d_in[3];  // (R,H,D)
    float* out = (float*)d_out;                  // (B,N,H)

    // Workspace layout
    unsigned short* nodesb = (unsigned short*)d_ws;                       // M*D bf16 = 16 MiB
    unsigned short* wb     = (unsigned short*)((char*)d_ws + (size_t)MM * DD * 2);      // 6*H*D bf16
    float*          inv_c  = (float*)((char*)d_ws + (size_t)MM * DD * 2 + (size_t)6 * HH * DD * 2);

    const int n_nodes = MM * DD;        // 8388608
    const int n_w0    = HH * DD;        // 65536
    const int n_wr    = RR * HH * DD;   // 327680

    cvt_kernel<<<n_nodes / 4 / 256, 256, 0, stream>>>(nodes, nodesb, n_nodes);
    cvt_kernel<<<n_w0 / 4 / 256, 256, 0, stream>>>(w0, wb, n_w0);
    cvt_kernel<<<n_wr / 4 / 256, 256, 0, stream>>>(wr, wb + n_w0, n_wr);

    rowsum_kernel<<<(BB * RR * NN) / 4, 256, 0, stream>>>(adj, inv_c);

    gemm_kernel<<<dim3(MM / 64, HH / 64), 256, 0, stream>>>(nodesb, wb, inv_c, out);
}

// Round 2
// 906.351 us; speedup vs baseline: 1.0624x; 1.0624x over previous
//
#include <hip/hip_runtime.h>
#include <hip/hip_bf16.h>

// Problem: B=32, R=5, N=1024, D=256, H=256
// out[b,n,h] = sum_d nodes[b,n,d]*w0[h,d]
//            + sum_r (1/c[b,r,n]) * sum_d nodes[b,n,d]*wr[r,h,d]
// c[b,r,n] = sum_j adj[b,r,n,j]  (1 if 0)

#define BB 32
#define RR 5
#define NN 1024
#define DD 256
#define HH 256
#define MM (BB * NN)   // 32768 global rows

typedef __attribute__((ext_vector_type(8))) short short8;
typedef __attribute__((ext_vector_type(4))) float f32x4;

#define GAS(p) ((const __attribute__((address_space(1))) void*)(p))
#define LAS(p) ((__attribute__((address_space(3))) void*)(p))

__device__ __forceinline__ unsigned short f2bf(float f) {
    unsigned int u = __float_as_uint(f);
    unsigned int r = (u + 0x7FFFu + ((u >> 16) & 1u)) >> 16;
    return (unsigned short)r;
}

// fp32 -> bf16 raw bits, 4 elems/thread. n must be multiple of 4.
__global__ void cvt_kernel(const float* __restrict__ in,
                           unsigned short* __restrict__ out, int n) {
    int i = (blockIdx.x * blockDim.x + threadIdx.x) * 4;
    if (i >= n) return;
    float4 v = *reinterpret_cast<const float4*>(in + i);
    ushort4 o;
    o.x = f2bf(v.x); o.y = f2bf(v.y); o.z = f2bf(v.z); o.w = f2bf(v.w);
    *reinterpret_cast<ushort4*>(out + i) = o;
}

// One wave per adjacency row (1024 floats). inv_c[b,r,n] = 1/max(rowsum, 0->1).
__global__ __launch_bounds__(256) void rowsum_kernel(const float* __restrict__ adj,
                                                     float* __restrict__ inv_c) {
    const int wave = blockIdx.x * 4 + (threadIdx.x >> 6);
    const int lane = threadIdx.x & 63;
    const float4* row4 = reinterpret_cast<const float4*>(adj + (size_t)wave * NN);
    float s = 0.f;
#pragma unroll
    for (int i = 0; i < 4; ++i) {
        float4 v = row4[lane + 64 * i];
        s += (v.x + v.y) + (v.z + v.w);
    }
#pragma unroll
    for (int off = 32; off > 0; off >>= 1) s += __shfl_down(s, off, 64);
    if (lane == 0) {
        float c = (s == 0.f) ? 1.f : s;
        inv_c[wave] = 1.f / c;
    }
}

// Fused 6-set GEMM + per-row combine.  m97-style 2-barrier K-loop.
// Block = 256 thr (4 waves). Block tile: 64 rows x 64 cols x 6 sets, BK=32.
// LDS: A 64x32 bf16 (4 KB) + B 6x64x32 bf16 (24 KB), staged via global_load_lds.
// Wave wv computes cols [wv*16, wv*16+16) for all 6 sets (acc = 6*4 f32x4/lane).
__global__ __launch_bounds__(256) void gemm_kernel(
    const unsigned short* __restrict__ nodesb,
    const unsigned short* __restrict__ wb,
    const float* __restrict__ inv_c,
    float* __restrict__ out) {
    __shared__ unsigned short smem[14336];  // 28 KB: [0,2048) A, [2048,14336) B
    __shared__ float s_inv[RR * 64];

    const int tid  = threadIdx.x;
    const int lane = tid & 63;
    const int wv   = tid >> 6;
    const int row_base = blockIdx.x * 64;
    const int col_base = blockIdx.y * 64;
    const int m    = lane & 15;
    const int quad = lane >> 4;

    // --- staging chunk setup: 28 x 1KB chunks, wave wv owns chunks wv*7..wv*7+6
    const unsigned short* gp[7];
    unsigned short*       lp[7];
#pragma unroll
    for (int j = 0; j < 7; ++j) {
        const int c = wv * 7 + j;
        lp[j] = smem + c * 512;                 // c*1024 bytes
        if (c < 4) {
            const int u   = c * 64 + lane;      // 16B-unit index in A region
            const int row = u >> 2;
            const int kc  = u & 3;
            gp[j] = nodesb + (size_t)(row_base + row) * DD + kc * 8;
        } else {
            const int u    = (c - 4) * 64 + lane;
            const int col6 = u >> 2;            // 0..383 : set*64 + col
            const int kc   = u & 3;
            const int set  = col6 >> 6;
            const int col  = col6 & 63;
            gp[j] = wb + (size_t)(set * HH + col_base + col) * DD + kc * 8;
        }
    }

    f32x4 acc[6][4];
#pragma unroll
    for (int s = 0; s < 6; ++s)
#pragma unroll
        for (int t = 0; t < 4; ++t) acc[s][t] = (f32x4){0.f, 0.f, 0.f, 0.f};

    const unsigned short* aL = smem + m * 32 + quad * 8;                  // +t*16*32
    const unsigned short* bL = smem + 2048 + (wv * 16 + m) * 32 + quad * 8; // +s*64*32

    for (int kt = 0; kt < 8; ++kt) {
        __syncthreads();   // LDS free to overwrite
#pragma unroll
        for (int j = 0; j < 7; ++j)
            __builtin_amdgcn_global_load_lds(GAS(gp[j] + kt * 32), LAS(lp[j]), 16, 0, 0);
        __syncthreads();   // staging complete

        short8 afr[4];
#pragma unroll
        for (int t = 0; t < 4; ++t)
            afr[t] = *reinterpret_cast<const short8*>(aL + t * 512);
#pragma unroll
        for (int s = 0; s < 6; ++s) {
            short8 bfr = *reinterpret_cast<const short8*>(bL + s * 2048);
#pragma unroll
            for (int t = 0; t < 4; ++t)
                acc[s][t] = __builtin_amdgcn_mfma_f32_16x16x32_bf16(afr[t], bfr, acc[s][t], 0, 0, 0);
        }
    }

    // --- epilogue: stage inv_c tile (5 x 64 floats) in LDS
    const int b  = row_base >> 10;
    const int n0 = row_base & (NN - 1);
    __syncthreads();
#pragma unroll
    for (int i = tid; i < RR * 64; i += 256) {
        const int r = i >> 6, nl = i & 63;
        s_inv[i] = inv_c[((size_t)b * RR + r) * NN + n0 + nl];
    }
    __syncthreads();

    const int hcol = col_base + wv * 16 + m;
#pragma unroll
    for (int t = 0; t < 4; ++t) {
#pragma unroll
        for (int i = 0; i < 4; ++i) {
            const int rloc = t * 16 + quad * 4 + i;
            float v = acc[0][t][i];
#pragma unroll
            for (int r = 0; r < RR; ++r)
                v += s_inv[r * 64 + rloc] * acc[r + 1][t][i];
            out[(size_t)(row_base + rloc) * HH + hcol] = v;
        }
    }
}

extern "C" void kernel_launch(void* const* d_in, const int* in_sizes, int n_in,
                              void* d_out, int out_size, void* d_ws, size_t ws_size,
                              hipStream_t stream) {
    const float* nodes = (const float*)d_in[0];  // (B,N,D)
    const float* adj   = (const float*)d_in[1];  // (B,R,N,N)
    const float* w0    = (const float*)d_in[2];  // (H,D)
    const float* wr    = (const float*)d_in[3];  // (R,H,D)
    float* out = (float*)d_out;                  // (B,N,H)

    // Workspace layout
    unsigned short* nodesb = (unsigned short*)d_ws;                                  // M*D bf16
    unsigned short* wb     = (unsigned short*)((char*)d_ws + (size_t)MM * DD * 2);   // 6*H*D bf16
    float*          inv_c  = (float*)((char*)d_ws + (size_t)MM * DD * 2 + (size_t)6 * HH * DD * 2);

    const int n_nodes = MM * DD;        // 8388608
    const int n_w0    = HH * DD;        // 65536
    const int n_wr    = RR * HH * DD;   // 327680

    cvt_kernel<<<n_nodes / 4 / 256, 256, 0, stream>>>(nodes, nodesb, n_nodes);
    cvt_kernel<<<n_w0 / 4 / 256, 256, 0, stream>>>(w0, wb, n_w0);
    cvt_kernel<<<n_wr / 4 / 256, 256, 0, stream>>>(wr, wb + n_w0, n_wr);

    rowsum_kernel<<<(BB * RR * NN) / 4, 256, 0, stream>>>(adj, inv_c);

    gemm_kernel<<<dim3(MM / 64, HH / 64), 256, 0, stream>>>(nodesb, wb, inv_c, out);
}